// Round 19
// baseline (182.741 us; speedup 1.0000x reference)
//
#include <hip/hip_runtime.h>
#include <stdint.h>
#include <stddef.h>

typedef __attribute__((ext_vector_type(8))) short bf16x8;
typedef __attribute__((ext_vector_type(4))) float f32x4;
typedef __attribute__((ext_vector_type(16))) float f32x16;

#define DMODEL 1536
#define TSEQ   2048
#define HDIM   128
#define NBR    3
#define NHB    4      // heads per branch
#define MROWS  4096   // B*T

__device__ __forceinline__ float bf2f(unsigned short u) {
  union { unsigned int i; float f; } v; v.i = ((unsigned int)u) << 16; return v.f;
}
__device__ __forceinline__ unsigned short f2bf(float f) {
  union { float f; unsigned int i; } v; v.f = f;
  unsigned int r = v.i + 0x7fffu + ((v.i >> 16) & 1u);
  return (unsigned short)(r >> 16);
}
__device__ __forceinline__ unsigned int cvtpk(float lo, float hi) {
  unsigned int r;
  asm("v_cvt_pk_bf16_f32 %0, %1, %2" : "=v"(r) : "v"(lo), "v"(hi));
  return r;
}
__device__ __forceinline__ void plswap(unsigned int& a, unsigned int& b) {
  asm("v_permlane32_swap_b32 %0, %1" : "+v"(a), "+v"(b));
}
__device__ __forceinline__ void gload_lds16(const void* g, void* l) {
  __builtin_amdgcn_global_load_lds((__attribute__((address_space(1))) void*)g,
                                   (__attribute__((address_space(3))) void*)l,
                                   16, 0, 0);
}

// ---------------------------------------------------------------------------
// Fused f32 -> bf16 conversion: X (6144 blks) | 9 weights (6912) | WO (2304)
// ---------------------------------------------------------------------------
struct CVT { const float* s[11]; };

__global__ __launch_bounds__(256) void k_cvt_all(
    CVT cv, unsigned short* __restrict__ Xbf, unsigned short* __restrict__ Wbf,
    unsigned short* __restrict__ WObf)
{
  const int bid = blockIdx.x;
  const float* __restrict__ src;
  unsigned short* __restrict__ dst;
  int i4;
  if (bid < 6144) {
    src = cv.s[0]; dst = Xbf; i4 = bid * 256 + threadIdx.x;
  } else if (bid < 13056) {
    int r = bid - 6144; int seg = r / 768; int inner = r - seg * 768;
    src = cv.s[1 + seg]; dst = Wbf + (size_t)seg * 786432;
    i4 = inner * 256 + threadIdx.x;
  } else {
    int r = bid - 13056; src = cv.s[10]; dst = WObf;
    i4 = r * 256 + threadIdx.x;
  }
  float4 v = ((const float4*)src)[i4];
  ushort4 o;
  o.x = f2bf(v.x); o.y = f2bf(v.y); o.z = f2bf(v.z); o.w = f2bf(v.w);
  ((ushort4*)dst)[i4] = o;
}

// ---------------------------------------------------------------------------
// Pipelined GEMM: tile 128x192x64, 8 waves, vmcnt(5), XOR-swizzled LDS.
// EPI==0: 2D XCD chunking (8m x 12n per XCD cell); V^T via LDS (nt stores).
// ---------------------------------------------------------------------------
#define GBM 128
#define GBN 192
#define GBK 64
#define GK  1536
#define GNT (GK / GBK)   // 24 K-tiles

template<int EPI>
__global__ __launch_bounds__(512, 4) void k_gemm8(
    const unsigned short* __restrict__ A, const unsigned short* __restrict__ Bw,
    unsigned short* __restrict__ Qs, unsigned short* __restrict__ Ksl,
    unsigned short* __restrict__ Vs, float* __restrict__ Cout)
{
  __shared__ __align__(16) unsigned short POOL[40960];   // 80 KiB
  unsigned short* As = POOL;            // 2*128*64 = 16384 u16
  unsigned short* Bs = POOL + 16384;    // 2*192*64 = 24576 u16
  unsigned short* LT = POOL;            // epilogue alias: [192][132] u16

  const int t = threadIdx.x, ln = t & 63, w = t >> 6;
  const int wm = w >> 2, wn = w & 3, g = ln >> 4, li = ln & 15;

  const int lid = blockIdx.y * gridDim.x + blockIdx.x;
  int m0, n0;
  if (EPI == 0) {
    const int xcd = lid & 7, idx = lid >> 3;
    m0 = (((xcd >> 1) << 3) + (idx & 7)) * GBM;
    n0 = ((xcd & 1) * 12 + (idx >> 3)) * GBN;
  } else {
    const int nwg = gridDim.x * gridDim.y;
    const int s = (lid & 7) * (nwg >> 3) + (lid >> 3);
    m0 = (s & 31) * GBM;
    n0 = (s >> 5) * GBN;
  }

  f32x4 zero4 = {0.f, 0.f, 0.f, 0.f};
  f32x4 acc[4][3];
#pragma unroll
  for (int i = 0; i < 4; ++i)
#pragma unroll
    for (int j = 0; j < 3; ++j) acc[i][j] = zero4;

  auto STAGE = [&](int p, int kt) {
    const unsigned short* Ag = A + (size_t)m0 * GK + kt * GBK;
    unsigned short* Al = As + p * (GBM * GBK);
#pragma unroll
    for (int i = 0; i < 2; ++i) {
      int ch = i * 512 + t; int r = ch >> 3, c = ch & 7;
      gload_lds16(Ag + (size_t)r * GK + ((c ^ (r & 7)) * 8), Al + ch * 8);
    }
    const unsigned short* Bg = Bw + (size_t)n0 * GK + kt * GBK;
    unsigned short* Bl = Bs + p * (GBN * GBK);
#pragma unroll
    for (int i = 0; i < 3; ++i) {
      int ch = i * 512 + t; int r = ch >> 3, c = ch & 7;
      gload_lds16(Bg + (size_t)r * GK + ((c ^ (r & 7)) * 8), Bl + ch * 8);
    }
  };

  STAGE(0, 0);
  STAGE(1, 1);

  for (int kt = 0; kt < GNT; ++kt) {
    const int cur = kt & 1;
    if (kt < GNT - 1) { asm volatile("s_waitcnt vmcnt(5)" ::: "memory"); }
    else              { asm volatile("s_waitcnt vmcnt(0)" ::: "memory"); }
    __builtin_amdgcn_sched_barrier(0);
    __builtin_amdgcn_s_barrier();
    __builtin_amdgcn_sched_barrier(0);
    asm volatile("" ::: "memory");

    const unsigned short* Al = As + cur * (GBM * GBK);
    const unsigned short* Bl = Bs + cur * (GBN * GBK);
#pragma unroll
    for (int kh = 0; kh < 2; ++kh) {
      bf16x8 af[4], bfn[3];
#pragma unroll
      for (int mf = 0; mf < 4; ++mf) {
        int r = wm * 64 + mf * 16 + li;
        af[mf] = *(const bf16x8*)(Al + r * 64 + (((kh * 4 + g) ^ (li & 7)) * 8));
      }
#pragma unroll
      for (int nf = 0; nf < 3; ++nf) {
        int r = wn * 48 + nf * 16 + li;
        bfn[nf] = *(const bf16x8*)(Bl + r * 64 + (((kh * 4 + g) ^ (li & 7)) * 8));
      }
      __builtin_amdgcn_s_setprio(1);
#pragma unroll
      for (int mf = 0; mf < 4; ++mf)
#pragma unroll
        for (int nf = 0; nf < 3; ++nf)
          acc[mf][nf] = __builtin_amdgcn_mfma_f32_16x16x32_bf16(
              af[mf], bfn[nf], acc[mf][nf], 0, 0, 0);
      __builtin_amdgcn_s_setprio(0);
    }
    asm volatile("" ::: "memory");
    __builtin_amdgcn_sched_barrier(0);
    __builtin_amdgcn_s_barrier();
    __builtin_amdgcn_sched_barrier(0);
    if (kt + 2 < GNT) STAGE(cur, kt + 2);
  }

  // ---- epilogue pass 1: Q/K scalar stores (coalesced cols) + V -> LT ----
  bool hasV = false;
  if (EPI == 0) {
    int matA = n0 >> 9, matB = (n0 + GBN - 1) >> 9;
    hasV = ((matA % 3) == 2) || ((matB % 3) == 2);
  }

#pragma unroll
  for (int mf = 0; mf < 4; ++mf)
#pragma unroll
    for (int nf = 0; nf < 3; ++nf) {
      int row0 = wm * 64 + mf * 16 + g * 4;   // tile row 0..127 (mult of 4)
      int colL = wn * 48 + nf * 16 + li;      // tile col 0..191
      int col  = n0 + colL;
      if (EPI == 0) {
        int mat = col >> 9, qkv = mat % 3;    // uniform within frag
        if (qkv == 2) {
          ushort4 o;
          o.x = f2bf(acc[mf][nf][0]); o.y = f2bf(acc[mf][nf][1]);
          o.z = f2bf(acc[mf][nf][2]); o.w = f2bf(acc[mf][nf][3]);
          *(ushort4*)(LT + colL * 132 + row0) = o;
        } else {
          int br = mat / 3;
          int within = col & 511;
          int h = within >> 7, d = within & 127;
          unsigned short* dst = (qkv == 0) ? Qs : Ksl;
#pragma unroll
          for (int rr = 0; rr < 4; ++rr) {
            int row = m0 + row0 + rr;
            int b = row >> 11, tt = row & 2047;
            dst[((size_t)((br * 2 + b) * 4 + h) * TSEQ + tt) * HDIM + d] =
                f2bf(acc[mf][nf][rr]);
          }
        }
      } else {
#pragma unroll
        for (int rr = 0; rr < 4; ++rr)
          Cout[(size_t)(m0 + row0 + rr) * DMODEL + col] = acc[mf][nf][rr];
      }
    }

  // ---- epilogue pass 2: LT -> coalesced V^T stores (non-temporal) ----
  if (EPI == 0 && hasV) {
    __syncthreads();
    const int bx = m0 >> 11, tb0 = m0 & 2047;
#pragma unroll
    for (int j = 0; j < 6; ++j) {
      int ch = j * 512 + t;            // 0..3071 = 192 cols x 16 t-chunks
      int ci = ch >> 4;
      int col = n0 + ci;
      int mat = col >> 9;
      if (mat % 3 == 2) {
        int within = col & 511;
        int hh = within >> 7, dd = within & 127;
        int brx = mat / 3;
        int t0c = (ch & 15) * 8;
        ushort4 lo  = *(const ushort4*)(LT + ci * 132 + t0c);
        ushort4 hi4 = *(const ushort4*)(LT + ci * 132 + t0c + 4);
        union { ushort4 a[2]; bf16x8 v; } u;
        u.a[0] = lo; u.a[1] = hi4;
        __builtin_nontemporal_store(u.v,
            (bf16x8*)(Vs + (size_t)((brx * 2 + bx) * 4 + hh) * (TSEQ * HDIM)
                         + (size_t)dd * TSEQ + tb0 + t0c));
      }
    }
  }
}

// ---------------------------------------------------------------------------
// RMSNorm + RoPE in place on Q,K slabs (bf16). 2 rows/wave, ushort2 access.
// ---------------------------------------------------------------------------
__global__ __launch_bounds__(256) void k_rope(
    unsigned short* __restrict__ Q, unsigned short* __restrict__ K,
    const float* __restrict__ qw, const float* __restrict__ kw)
{
  const int t = threadIdx.x, l = t & 63, w = t >> 6;
  const int r = l >> 5, j = l & 31;
  const int rid = blockIdx.x * 8 + w * 2 + r;   // 0..49151
  const int tt  = rid & (TSEQ - 1);
  const size_t base = (size_t)rid * HDIM;

  const float a0 = (float)tt * exp2f(-0.31143075464f * (float)(2 * j));
  const float a1 = (float)tt * exp2f(-0.31143075464f * (float)(2 * j + 1));
  float s0, c0, s1, c1;
  sincosf(a0, &s0, &c0);
  sincosf(a1, &s1, &c1);

#pragma unroll
  for (int which = 0; which < 2; ++which) {
    unsigned short* P = which ? K : Q;
    const float* Wn = which ? kw : qw;
    ushort2 u1 = *(const ushort2*)(P + base + 2 * j);
    ushort2 u2 = *(const ushort2*)(P + base + 64 + 2 * j);
    float x10 = bf2f(u1.x), x11 = bf2f(u1.y);
    float x20 = bf2f(u2.x), x21 = bf2f(u2.y);
    float ss = (x10 * x10 + x11 * x11) + (x20 * x20 + x21 * x21);
#pragma unroll
    for (int off = 1; off < 32; off <<= 1) ss += __shfl_xor(ss, off, 64);
    float rr = rsqrtf(ss * (1.0f / 128.0f) + 1.1920928955078125e-07f);
    float2 w1 = *(const float2*)(Wn + 2 * j);
    float2 w2 = *(const float2*)(Wn + 64 + 2 * j);
    float y10 = x10 * rr * w1.x, y11 = x11 * rr * w1.y;
    float y20 = x20 * rr * w2.x, y21 = x21 * rr * w2.y;
    ushort2 o1, o2;
    o1.x = f2bf(y10 * c0 - y20 * s0); o1.y = f2bf(y11 * c1 - y21 * s1);
    o2.x = f2bf(y20 * c0 + y10 * s0); o2.y = f2bf(y21 * c1 + y11 * s1);
    *(ushort2*)(P + base + 2 * j)      = o1;
    *(ushort2*)(P + base + 64 + 2 * j) = o2;
  }
}

// ---------------------------------------------------------------------------
// Flash attention (R13 structure + defer-max + XCD affinity).
// R19: causal / anti-causal / bidir each in their OWN block (grid z=3) —
// the fused 256-block grid left 1 block/CU while LDS+VGPR allow 2;
// 384 variable-length blocks pack at ~1.5 blocks/CU -> cross-block overlap.
// ---------------------------------------------------------------------------
#define ATT_SCALE 0.08838834764831845f

template<int MODE>
__device__ __forceinline__ void flash_phase(
    int qt, int bh,
    const unsigned short* __restrict__ Q, const unsigned short* __restrict__ K,
    const unsigned short* __restrict__ VT, unsigned short* __restrict__ AO,
    unsigned short* SH)
{
  const int b = bh >> 2, h = bh & 3;
  const int t = threadIdx.x, l = t & 63, w = t >> 6;
  const int hi = l >> 5, l31 = l & 31;
  const int wq = w & 3, gid = w >> 2;
  const size_t slab = (size_t)(MODE * 8 + bh) * (TSEQ * HDIM);
  const int q0 = qt * 128;

  unsigned short* KsG = SH + gid * 17920;        // [64][136] u16
  unsigned short* VtG = KsG + 8704;              // [128][72] u16

  bf16x8 qf[8];
  {
    const unsigned short* qp = Q + slab + (size_t)(q0 + wq*32 + l31) * HDIM + hi*8;
#pragma unroll
    for (int st = 0; st < 8; ++st) qf[st] = *(const bf16x8*)(qp + st*16);
  }

  f32x16 zero16;
#pragma unroll
  for (int e = 0; e < 16; ++e) zero16[e] = 0.f;
  f32x16 acc[4];
#pragma unroll
  for (int df = 0; df < 4; ++df) acc[df] = zero16;
  float m_run = -1e30f, l_run = 0.f;

  int n, ktbase, diagAt;
  if (MODE == 0)      { n = qt + 1;  ktbase = gid;          diagAt = n - 1; }
  else if (MODE == 1) { n = 16 - qt; ktbase = 2*qt + gid;   diagAt = 0; }
  else                { n = 16;      ktbase = gid;          diagAt = -1; }

  const int tl = t & 255;
  bf16x8 rk[4], rv[4];
  auto LOADT = [&](int kt) {
    const int k0 = kt * 64;
#pragma unroll
    for (int j = 0; j < 4; ++j) {
      int c = j * 256 + tl;
      rk[j] = *(const bf16x8*)(K  + slab + (size_t)(k0 + (c >> 4)) * HDIM + (c & 15) * 8);
      rv[j] = *(const bf16x8*)(VT + slab + (size_t)(c >> 3) * TSEQ + k0 + (c & 7) * 8);
    }
  };

  LOADT(ktbase);

  for (int i = 0; i < n; ++i) {
    const int kt = ktbase + 2 * i;
    const int k0 = kt * 64;
    __syncthreads();
#pragma unroll
    for (int j = 0; j < 4; ++j) {
      int c = j * 256 + tl;
      *(bf16x8*)(KsG + (c >> 4) * 136 + (c & 15) * 8) = rk[j];
      *(bf16x8*)(VtG + (c >> 3) * 72  + (c & 7) * 8)  = rv[j];
    }
    if (i + 1 < n) LOADT(kt + 2);
    __syncthreads();

    f32x16 sf0 = zero16, sf1 = zero16;
#pragma unroll
    for (int st = 0; st < 8; ++st) {
      bf16x8 kf0 = *(const bf16x8*)(KsG + l31 * 136 + st*16 + hi*8);
      bf16x8 kf1 = *(const bf16x8*)(KsG + (32 + l31) * 136 + st*16 + hi*8);
      __builtin_amdgcn_s_setprio(1);
      sf0 = __builtin_amdgcn_mfma_f32_32x32x16_bf16(kf0, qf[st], sf0, 0, 0, 0);
      sf1 = __builtin_amdgcn_mfma_f32_32x32x16_bf16(kf1, qf[st], sf1, 0, 0, 0);
      __builtin_amdgcn_s_setprio(0);
    }

    float pf[32];
#pragma unroll
    for (int r = 0; r < 16; ++r) { pf[r] = sf0[r] * ATT_SCALE; pf[16+r] = sf1[r] * ATT_SCALE; }

    if (MODE != 2 && i == diagAt) {
      const int qg = q0 + wq*32 + l31;
#pragma unroll
      for (int f = 0; f < 2; ++f)
#pragma unroll
        for (int r = 0; r < 16; ++r) {
          int kg = k0 + f*32 + 4*hi + (r & 3) + 8*(r >> 2);
          bool ok = (MODE == 0) ? (kg <= qg) : (kg >= qg);
          if (!ok) pf[f*16 + r] = -1e30f;
        }
    }

    float m = pf[0];
#pragma unroll
    for (int j = 1; j < 32; ++j) m = fmaxf(m, pf[j]);
    m = fmaxf(m, __shfl_xor(m, 32, 64));

    // T13 defer-max: rescale only when max grew by > 8 (P bounded by e^8)
    if (__any(m - m_run > 8.0f)) {
      float mn = fmaxf(m_run, m);
      float alpha = __expf(m_run - mn);
      m_run = mn;
      l_run *= alpha;
#pragma unroll
      for (int df = 0; df < 4; ++df) acc[df] *= alpha;
    }

    float rs0 = 0.f, rs1 = 0.f, rs2 = 0.f, rs3 = 0.f;
#pragma unroll
    for (int j = 0; j < 8; ++j) { pf[j]    = __expf(pf[j]    - m_run); rs0 += pf[j]; }
#pragma unroll
    for (int j = 8; j < 16; ++j){ pf[j]    = __expf(pf[j]    - m_run); rs1 += pf[j]; }
#pragma unroll
    for (int j = 0; j < 8; ++j) { pf[16+j] = __expf(pf[16+j] - m_run); rs2 += pf[16+j]; }
#pragma unroll
    for (int j = 8; j < 16; ++j){ pf[16+j] = __expf(pf[16+j] - m_run); rs3 += pf[16+j]; }
    float rs = (rs0 + rs1) + (rs2 + rs3);
    rs += __shfl_xor(rs, 32, 64);
    l_run += rs;

    unsigned int pb[2][8];
#pragma unroll
    for (int f = 0; f < 2; ++f) {
#pragma unroll
      for (int u = 0; u < 4; ++u) {
        pb[f][2*u]   = cvtpk(pf[f*16 + 4*u + 0], pf[f*16 + 4*u + 1]);
        pb[f][2*u+1] = cvtpk(pf[f*16 + 4*u + 2], pf[f*16 + 4*u + 3]);
      }
      plswap(pb[f][0], pb[f][2]);
      plswap(pb[f][1], pb[f][3]);
      plswap(pb[f][4], pb[f][6]);
      plswap(pb[f][5], pb[f][7]);
    }

#pragma unroll
    for (int s = 0; s < 4; ++s) {
      union { unsigned int u[4]; bf16x8 v; } pbv;
#pragma unroll
      for (int u = 0; u < 4; ++u) pbv.u[u] = pb[s >> 1][(s & 1) * 4 + u];
#pragma unroll
      for (int df = 0; df < 4; ++df) {
        bf16x8 vb = *(const bf16x8*)(VtG + (df*32 + l31) * 72 + s*16 + hi*8);
        __builtin_amdgcn_s_setprio(1);
        acc[df] = __builtin_amdgcn_mfma_f32_32x32x16_bf16(vb, pbv.v, acc[df], 0, 0, 0);
        __builtin_amdgcn_s_setprio(0);
      }
    }
  }

  // ---- split-K combine ----
  __syncthreads();
  float* EXf = (float*)SH;                       // [4][64][68] f32
  float* MLf = (float*)(SH + 35840);             // [4][64][2]  f32
  if (gid == 1) {
    MLf[(wq*64 + l)*2 + 0] = m_run;
    MLf[(wq*64 + l)*2 + 1] = l_run;
#pragma unroll
    for (int df = 0; df < 4; ++df)
#pragma unroll
      for (int u = 0; u < 4; ++u) {
        f32x4 ch = {acc[df][4*u], acc[df][4*u+1], acc[df][4*u+2], acc[df][4*u+3]};
        *(f32x4*)&EXf[(wq*64 + l)*68 + df*16 + u*4] = ch;
      }
  }
  __syncthreads();
  if (gid == 0) {
    float mB = MLf[(wq*64 + l)*2 + 0];
    float lB = MLf[(wq*64 + l)*2 + 1];
    float mF = fmaxf(m_run, mB);
    float a0 = __expf(m_run - mF), a1 = __expf(mB - mF);
    float inv = 1.0f / (l_run * a0 + lB * a1);
    a0 *= inv; a1 *= inv;
#pragma unroll
    for (int df = 0; df < 4; ++df)
#pragma unroll
      for (int u = 0; u < 4; ++u) {
        f32x4 cb = *(const f32x4*)&EXf[(wq*64 + l)*68 + df*16 + u*4];
#pragma unroll
        for (int e = 0; e < 4; ++e)
          acc[df][4*u+e] = acc[df][4*u+e] * a0 + cb[e] * a1;
      }
  }
  __syncthreads();

  // ---- transpose epilogue ----
  unsigned int* OT = (unsigned int*)SH;
  if (gid == 0) {
#pragma unroll
    for (int df = 0; df < 4; ++df)
#pragma unroll
      for (int u = 0; u < 4; ++u) {
        unsigned int d0 = cvtpk(acc[df][4*u+0], acc[df][4*u+1]);
        unsigned int d1 = cvtpk(acc[df][4*u+2], acc[df][4*u+3]);
        uint2 dd; dd.x = d0; dd.y = d1;
        *(uint2*)&OT[(wq*32 + l31)*68 + df*16 + 2*hi + 4*u] = dd;
      }
  }
  __syncthreads();
  {
    const int q = t >> 2, sg = t & 3;
    size_t rowbase = ((size_t)b * TSEQ + q0 + q) * DMODEL + MODE * 512 + h * HDIM;
#pragma unroll
    for (int u = 0; u < 4; ++u) {
      bf16x8 vv = *(const bf16x8*)&OT[q*68 + u*16 + sg*4];
      *(bf16x8*)(AO + rowbase + (u*16 + sg*4)*2) = vv;
    }
  }
}

// grid (8, 16, 3): x=bh (lid%8 -> XCD), y=qt, z=branch (0 causal, 1 anti, 2 bidir)
__global__ __launch_bounds__(512, 2) void k_attn(
    const unsigned short* __restrict__ Q, const unsigned short* __restrict__ K,
    const unsigned short* __restrict__ VT, unsigned short* __restrict__ AO)
{
  __shared__ __align__(16) unsigned short SH[36864];   // 73,728 B

  const int bh = blockIdx.x;
  const int qt = blockIdx.y;
  if (blockIdx.z == 0) {
    flash_phase<0>(qt, bh, Q, K, VT, AO, SH);
  } else if (blockIdx.z == 1) {
    flash_phase<1>(qt, bh, Q, K, VT, AO, SH);
  } else {
    flash_phase<2>(qt, bh, Q, K, VT, AO, SH);
  }
}

// ---------------------------------------------------------------------------
extern "C" void kernel_launch(void* const* d_in, const int* in_sizes, int n_in,
                              void* d_out, int out_size, void* d_ws, size_t ws_size,
                              hipStream_t stream)
{
  (void)in_sizes; (void)n_in; (void)out_size; (void)ws_size;
  const float* qw  = (const float*)d_in[11];
  const float* kw  = (const float*)d_in[12];

  const size_t S = (size_t)NBR * 2 * NHB * TSEQ * HDIM;       // 6,291,456 elems
  unsigned short* Qs   = (unsigned short*)d_ws;                // S
  unsigned short* Ks   = Qs + S;                               // S
  unsigned short* Vs   = Ks + S;                               // S (holds V^T)
  unsigned short* AO   = Vs + S;                               // S
  unsigned short* Xbf  = AO + S;                               // S (= MROWS*DMODEL)
  unsigned short* Wbf  = Xbf + (size_t)MROWS * DMODEL;         // 9*512*1536
  unsigned short* WObf = Wbf + (size_t)9 * 512 * DMODEL;       // 1536*1536
  float* Cout = (float*)d_out;

  // fused conversion: X | 9 QKV weights | WO
  CVT cv;
  cv.s[0] = (const float*)d_in[0];
  for (int i = 0; i < 9; ++i) cv.s[1 + i] = (const float*)d_in[1 + i];
  cv.s[10] = (const float*)d_in[10];
  k_cvt_all<<<dim3(15360), dim3(256), 0, stream>>>(cv, Xbf, Wbf, WObf);

  // fused QKV projection: [4096, 4608] = X @ Wall^T (V written as V^T, nt)
  k_gemm8<0><<<dim3(32, 24), dim3(512), 0, stream>>>(Xbf, Wbf, Qs, Ks, Vs, nullptr);
  k_rope<<<dim3(6144), dim3(256), 0, stream>>>(Qs, Ks, qw, kw);
  k_attn<<<dim3(8, 16, 3), dim3(512), 0, stream>>>(Qs, Ks, Vs, AO);
  // output projection: [4096, 1536] = AO @ wo^T
  k_gemm8<1><<<dim3(32, 8), dim3(512), 0, stream>>>(AO, WObf, nullptr, nullptr, nullptr, Cout);
}

// Round 20
// 170.066 us; speedup vs baseline: 1.0745x; 1.0745x over previous
//
#include <hip/hip_runtime.h>
#include <stdint.h>
#include <stddef.h>

typedef __attribute__((ext_vector_type(8))) short bf16x8;
typedef __attribute__((ext_vector_type(4))) float f32x4;
typedef __attribute__((ext_vector_type(16))) float f32x16;

#define DMODEL 1536
#define TSEQ   2048
#define HDIM   128
#define NBR    3
#define NHB    4      // heads per branch
#define MROWS  4096   // B*T

__device__ __forceinline__ float bf2f(unsigned short u) {
  union { unsigned int i; float f; } v; v.i = ((unsigned int)u) << 16; return v.f;
}
__device__ __forceinline__ unsigned short f2bf(float f) {
  union { float f; unsigned int i; } v; v.f = f;
  unsigned int r = v.i + 0x7fffu + ((v.i >> 16) & 1u);
  return (unsigned short)(r >> 16);
}
__device__ __forceinline__ unsigned int cvtpk(float lo, float hi) {
  unsigned int r;
  asm("v_cvt_pk_bf16_f32 %0, %1, %2" : "=v"(r) : "v"(lo), "v"(hi));
  return r;
}
__device__ __forceinline__ void plswap(unsigned int& a, unsigned int& b) {
  asm("v_permlane32_swap_b32 %0, %1" : "+v"(a), "+v"(b));
}
__device__ __forceinline__ void gload_lds16(const void* g, void* l) {
  __builtin_amdgcn_global_load_lds((__attribute__((address_space(1))) void*)g,
                                   (__attribute__((address_space(3))) void*)l,
                                   16, 0, 0);
}

// ---------------------------------------------------------------------------
// Fused f32 -> bf16 conversion: X (6144 blks) | 9 weights (6912) | WO (2304)
// ---------------------------------------------------------------------------
struct CVT { const float* s[11]; };

__global__ __launch_bounds__(256) void k_cvt_all(
    CVT cv, unsigned short* __restrict__ Xbf, unsigned short* __restrict__ Wbf,
    unsigned short* __restrict__ WObf)
{
  const int bid = blockIdx.x;
  const float* __restrict__ src;
  unsigned short* __restrict__ dst;
  int i4;
  if (bid < 6144) {
    src = cv.s[0]; dst = Xbf; i4 = bid * 256 + threadIdx.x;
  } else if (bid < 13056) {
    int r = bid - 6144; int seg = r / 768; int inner = r - seg * 768;
    src = cv.s[1 + seg]; dst = Wbf + (size_t)seg * 786432;
    i4 = inner * 256 + threadIdx.x;
  } else {
    int r = bid - 13056; src = cv.s[10]; dst = WObf;
    i4 = r * 256 + threadIdx.x;
  }
  float4 v = ((const float4*)src)[i4];
  ushort4 o;
  o.x = f2bf(v.x); o.y = f2bf(v.y); o.z = f2bf(v.z); o.w = f2bf(v.w);
  ((ushort4*)dst)[i4] = o;
}

// ---------------------------------------------------------------------------
// Pipelined GEMM: tile 128x192x64, 8 waves, vmcnt(5), XOR-swizzled LDS.
// EPI==0: 2D XCD chunking (8m x 12n per XCD cell); V^T via LDS (nt stores).
// ---------------------------------------------------------------------------
#define GBM 128
#define GBN 192
#define GBK 64
#define GK  1536
#define GNT (GK / GBK)   // 24 K-tiles

template<int EPI>
__global__ __launch_bounds__(512, 4) void k_gemm8(
    const unsigned short* __restrict__ A, const unsigned short* __restrict__ Bw,
    unsigned short* __restrict__ Qs, unsigned short* __restrict__ Ksl,
    unsigned short* __restrict__ Vs, float* __restrict__ Cout)
{
  __shared__ __align__(16) unsigned short POOL[40960];   // 80 KiB
  unsigned short* As = POOL;            // 2*128*64 = 16384 u16
  unsigned short* Bs = POOL + 16384;    // 2*192*64 = 24576 u16
  unsigned short* LT = POOL;            // epilogue alias: [192][132] u16

  const int t = threadIdx.x, ln = t & 63, w = t >> 6;
  const int wm = w >> 2, wn = w & 3, g = ln >> 4, li = ln & 15;

  const int lid = blockIdx.y * gridDim.x + blockIdx.x;
  int m0, n0;
  if (EPI == 0) {
    const int xcd = lid & 7, idx = lid >> 3;
    m0 = (((xcd >> 1) << 3) + (idx & 7)) * GBM;
    n0 = ((xcd & 1) * 12 + (idx >> 3)) * GBN;
  } else {
    const int nwg = gridDim.x * gridDim.y;
    const int s = (lid & 7) * (nwg >> 3) + (lid >> 3);
    m0 = (s & 31) * GBM;
    n0 = (s >> 5) * GBN;
  }

  f32x4 zero4 = {0.f, 0.f, 0.f, 0.f};
  f32x4 acc[4][3];
#pragma unroll
  for (int i = 0; i < 4; ++i)
#pragma unroll
    for (int j = 0; j < 3; ++j) acc[i][j] = zero4;

  auto STAGE = [&](int p, int kt) {
    const unsigned short* Ag = A + (size_t)m0 * GK + kt * GBK;
    unsigned short* Al = As + p * (GBM * GBK);
#pragma unroll
    for (int i = 0; i < 2; ++i) {
      int ch = i * 512 + t; int r = ch >> 3, c = ch & 7;
      gload_lds16(Ag + (size_t)r * GK + ((c ^ (r & 7)) * 8), Al + ch * 8);
    }
    const unsigned short* Bg = Bw + (size_t)n0 * GK + kt * GBK;
    unsigned short* Bl = Bs + p * (GBN * GBK);
#pragma unroll
    for (int i = 0; i < 3; ++i) {
      int ch = i * 512 + t; int r = ch >> 3, c = ch & 7;
      gload_lds16(Bg + (size_t)r * GK + ((c ^ (r & 7)) * 8), Bl + ch * 8);
    }
  };

  STAGE(0, 0);
  STAGE(1, 1);

  for (int kt = 0; kt < GNT; ++kt) {
    const int cur = kt & 1;
    if (kt < GNT - 1) { asm volatile("s_waitcnt vmcnt(5)" ::: "memory"); }
    else              { asm volatile("s_waitcnt vmcnt(0)" ::: "memory"); }
    __builtin_amdgcn_sched_barrier(0);
    __builtin_amdgcn_s_barrier();
    __builtin_amdgcn_sched_barrier(0);
    asm volatile("" ::: "memory");

    const unsigned short* Al = As + cur * (GBM * GBK);
    const unsigned short* Bl = Bs + cur * (GBN * GBK);
#pragma unroll
    for (int kh = 0; kh < 2; ++kh) {
      bf16x8 af[4], bfn[3];
#pragma unroll
      for (int mf = 0; mf < 4; ++mf) {
        int r = wm * 64 + mf * 16 + li;
        af[mf] = *(const bf16x8*)(Al + r * 64 + (((kh * 4 + g) ^ (li & 7)) * 8));
      }
#pragma unroll
      for (int nf = 0; nf < 3; ++nf) {
        int r = wn * 48 + nf * 16 + li;
        bfn[nf] = *(const bf16x8*)(Bl + r * 64 + (((kh * 4 + g) ^ (li & 7)) * 8));
      }
      __builtin_amdgcn_s_setprio(1);
#pragma unroll
      for (int mf = 0; mf < 4; ++mf)
#pragma unroll
        for (int nf = 0; nf < 3; ++nf)
          acc[mf][nf] = __builtin_amdgcn_mfma_f32_16x16x32_bf16(
              af[mf], bfn[nf], acc[mf][nf], 0, 0, 0);
      __builtin_amdgcn_s_setprio(0);
    }
    asm volatile("" ::: "memory");
    __builtin_amdgcn_sched_barrier(0);
    __builtin_amdgcn_s_barrier();
    __builtin_amdgcn_sched_barrier(0);
    if (kt + 2 < GNT) STAGE(cur, kt + 2);
  }

  // ---- epilogue pass 1: Q/K scalar stores (coalesced cols) + V -> LT ----
  bool hasV = false;
  if (EPI == 0) {
    int matA = n0 >> 9, matB = (n0 + GBN - 1) >> 9;
    hasV = ((matA % 3) == 2) || ((matB % 3) == 2);
  }

#pragma unroll
  for (int mf = 0; mf < 4; ++mf)
#pragma unroll
    for (int nf = 0; nf < 3; ++nf) {
      int row0 = wm * 64 + mf * 16 + g * 4;   // tile row 0..127 (mult of 4)
      int colL = wn * 48 + nf * 16 + li;      // tile col 0..191
      int col  = n0 + colL;
      if (EPI == 0) {
        int mat = col >> 9, qkv = mat % 3;    // uniform within frag
        if (qkv == 2) {
          ushort4 o;
          o.x = f2bf(acc[mf][nf][0]); o.y = f2bf(acc[mf][nf][1]);
          o.z = f2bf(acc[mf][nf][2]); o.w = f2bf(acc[mf][nf][3]);
          *(ushort4*)(LT + colL * 132 + row0) = o;
        } else {
          int br = mat / 3;
          int within = col & 511;
          int h = within >> 7, d = within & 127;
          unsigned short* dst = (qkv == 0) ? Qs : Ksl;
#pragma unroll
          for (int rr = 0; rr < 4; ++rr) {
            int row = m0 + row0 + rr;
            int b = row >> 11, tt = row & 2047;
            dst[((size_t)((br * 2 + b) * 4 + h) * TSEQ + tt) * HDIM + d] =
                f2bf(acc[mf][nf][rr]);
          }
        }
      } else {
#pragma unroll
        for (int rr = 0; rr < 4; ++rr)
          Cout[(size_t)(m0 + row0 + rr) * DMODEL + col] = acc[mf][nf][rr];
      }
    }

  // ---- epilogue pass 2: LT -> coalesced V^T stores (non-temporal) ----
  if (EPI == 0 && hasV) {
    __syncthreads();
    const int bx = m0 >> 11, tb0 = m0 & 2047;
#pragma unroll
    for (int j = 0; j < 6; ++j) {
      int ch = j * 512 + t;            // 0..3071 = 192 cols x 16 t-chunks
      int ci = ch >> 4;
      int col = n0 + ci;
      int mat = col >> 9;
      if (mat % 3 == 2) {
        int within = col & 511;
        int hh = within >> 7, dd = within & 127;
        int brx = mat / 3;
        int t0c = (ch & 15) * 8;
        ushort4 lo  = *(const ushort4*)(LT + ci * 132 + t0c);
        ushort4 hi4 = *(const ushort4*)(LT + ci * 132 + t0c + 4);
        union { ushort4 a[2]; bf16x8 v; } u;
        u.a[0] = lo; u.a[1] = hi4;
        __builtin_nontemporal_store(u.v,
            (bf16x8*)(Vs + (size_t)((brx * 2 + bx) * 4 + hh) * (TSEQ * HDIM)
                         + (size_t)dd * TSEQ + tb0 + t0c));
      }
    }
  }
}

// ---------------------------------------------------------------------------
// RMSNorm + RoPE in place on Q,K slabs (bf16). 2 rows/wave, ushort2 access.
// ---------------------------------------------------------------------------
__global__ __launch_bounds__(256) void k_rope(
    unsigned short* __restrict__ Q, unsigned short* __restrict__ K,
    const float* __restrict__ qw, const float* __restrict__ kw)
{
  const int t = threadIdx.x, l = t & 63, w = t >> 6;
  const int r = l >> 5, j = l & 31;
  const int rid = blockIdx.x * 8 + w * 2 + r;   // 0..49151
  const int tt  = rid & (TSEQ - 1);
  const size_t base = (size_t)rid * HDIM;

  const float a0 = (float)tt * exp2f(-0.31143075464f * (float)(2 * j));
  const float a1 = (float)tt * exp2f(-0.31143075464f * (float)(2 * j + 1));
  float s0, c0, s1, c1;
  sincosf(a0, &s0, &c0);
  sincosf(a1, &s1, &c1);

#pragma unroll
  for (int which = 0; which < 2; ++which) {
    unsigned short* P = which ? K : Q;
    const float* Wn = which ? kw : qw;
    ushort2 u1 = *(const ushort2*)(P + base + 2 * j);
    ushort2 u2 = *(const ushort2*)(P + base + 64 + 2 * j);
    float x10 = bf2f(u1.x), x11 = bf2f(u1.y);
    float x20 = bf2f(u2.x), x21 = bf2f(u2.y);
    float ss = (x10 * x10 + x11 * x11) + (x20 * x20 + x21 * x21);
#pragma unroll
    for (int off = 1; off < 32; off <<= 1) ss += __shfl_xor(ss, off, 64);
    float rr = rsqrtf(ss * (1.0f / 128.0f) + 1.1920928955078125e-07f);
    float2 w1 = *(const float2*)(Wn + 2 * j);
    float2 w2 = *(const float2*)(Wn + 64 + 2 * j);
    float y10 = x10 * rr * w1.x, y11 = x11 * rr * w1.y;
    float y20 = x20 * rr * w2.x, y21 = x21 * rr * w2.y;
    ushort2 o1, o2;
    o1.x = f2bf(y10 * c0 - y20 * s0); o1.y = f2bf(y11 * c1 - y21 * s1);
    o2.x = f2bf(y20 * c0 + y10 * s0); o2.y = f2bf(y21 * c1 + y11 * s1);
    *(ushort2*)(P + base + 2 * j)      = o1;
    *(ushort2*)(P + base + 64 + 2 * j) = o2;
  }
}

// ---------------------------------------------------------------------------
// Flash attention (R13 structure + defer-max + XCD affinity).
// R18 grid: (8=bh, 16=qt, 2) fused causal+anti in z=0 — balanced 17/16-visit
// blocks at 1/CU beat R19's 384-block oversubscription (which idled 64 CUs).
// ---------------------------------------------------------------------------
#define ATT_SCALE 0.08838834764831845f

template<int MODE>
__device__ __forceinline__ void flash_phase(
    int qt, int bh,
    const unsigned short* __restrict__ Q, const unsigned short* __restrict__ K,
    const unsigned short* __restrict__ VT, unsigned short* __restrict__ AO,
    unsigned short* SH)
{
  const int b = bh >> 2, h = bh & 3;
  const int t = threadIdx.x, l = t & 63, w = t >> 6;
  const int hi = l >> 5, l31 = l & 31;
  const int wq = w & 3, gid = w >> 2;
  const size_t slab = (size_t)(MODE * 8 + bh) * (TSEQ * HDIM);
  const int q0 = qt * 128;

  unsigned short* KsG = SH + gid * 17920;        // [64][136] u16
  unsigned short* VtG = KsG + 8704;              // [128][72] u16

  bf16x8 qf[8];
  {
    const unsigned short* qp = Q + slab + (size_t)(q0 + wq*32 + l31) * HDIM + hi*8;
#pragma unroll
    for (int st = 0; st < 8; ++st) qf[st] = *(const bf16x8*)(qp + st*16);
  }

  f32x16 zero16;
#pragma unroll
  for (int e = 0; e < 16; ++e) zero16[e] = 0.f;
  f32x16 acc[4];
#pragma unroll
  for (int df = 0; df < 4; ++df) acc[df] = zero16;
  float m_run = -1e30f, l_run = 0.f;

  int n, ktbase, diagAt;
  if (MODE == 0)      { n = qt + 1;  ktbase = gid;          diagAt = n - 1; }
  else if (MODE == 1) { n = 16 - qt; ktbase = 2*qt + gid;   diagAt = 0; }
  else                { n = 16;      ktbase = gid;          diagAt = -1; }

  const int tl = t & 255;
  bf16x8 rk[4], rv[4];
  auto LOADT = [&](int kt) {
    const int k0 = kt * 64;
#pragma unroll
    for (int j = 0; j < 4; ++j) {
      int c = j * 256 + tl;
      rk[j] = *(const bf16x8*)(K  + slab + (size_t)(k0 + (c >> 4)) * HDIM + (c & 15) * 8);
      rv[j] = *(const bf16x8*)(VT + slab + (size_t)(c >> 3) * TSEQ + k0 + (c & 7) * 8);
    }
  };

  LOADT(ktbase);

  for (int i = 0; i < n; ++i) {
    const int kt = ktbase + 2 * i;
    const int k0 = kt * 64;
    __syncthreads();
#pragma unroll
    for (int j = 0; j < 4; ++j) {
      int c = j * 256 + tl;
      *(bf16x8*)(KsG + (c >> 4) * 136 + (c & 15) * 8) = rk[j];
      *(bf16x8*)(VtG + (c >> 3) * 72  + (c & 7) * 8)  = rv[j];
    }
    if (i + 1 < n) LOADT(kt + 2);
    __syncthreads();

    f32x16 sf0 = zero16, sf1 = zero16;
#pragma unroll
    for (int st = 0; st < 8; ++st) {
      bf16x8 kf0 = *(const bf16x8*)(KsG + l31 * 136 + st*16 + hi*8);
      bf16x8 kf1 = *(const bf16x8*)(KsG + (32 + l31) * 136 + st*16 + hi*8);
      __builtin_amdgcn_s_setprio(1);
      sf0 = __builtin_amdgcn_mfma_f32_32x32x16_bf16(kf0, qf[st], sf0, 0, 0, 0);
      sf1 = __builtin_amdgcn_mfma_f32_32x32x16_bf16(kf1, qf[st], sf1, 0, 0, 0);
      __builtin_amdgcn_s_setprio(0);
    }

    float pf[32];
#pragma unroll
    for (int r = 0; r < 16; ++r) { pf[r] = sf0[r] * ATT_SCALE; pf[16+r] = sf1[r] * ATT_SCALE; }

    if (MODE != 2 && i == diagAt) {
      const int qg = q0 + wq*32 + l31;
#pragma unroll
      for (int f = 0; f < 2; ++f)
#pragma unroll
        for (int r = 0; r < 16; ++r) {
          int kg = k0 + f*32 + 4*hi + (r & 3) + 8*(r >> 2);
          bool ok = (MODE == 0) ? (kg <= qg) : (kg >= qg);
          if (!ok) pf[f*16 + r] = -1e30f;
        }
    }

    float m = pf[0];
#pragma unroll
    for (int j = 1; j < 32; ++j) m = fmaxf(m, pf[j]);
    m = fmaxf(m, __shfl_xor(m, 32, 64));

    // T13 defer-max: rescale only when max grew by > 8 (P bounded by e^8)
    if (__any(m - m_run > 8.0f)) {
      float mn = fmaxf(m_run, m);
      float alpha = __expf(m_run - mn);
      m_run = mn;
      l_run *= alpha;
#pragma unroll
      for (int df = 0; df < 4; ++df) acc[df] *= alpha;
    }

    float rs0 = 0.f, rs1 = 0.f, rs2 = 0.f, rs3 = 0.f;
#pragma unroll
    for (int j = 0; j < 8; ++j) { pf[j]    = __expf(pf[j]    - m_run); rs0 += pf[j]; }
#pragma unroll
    for (int j = 8; j < 16; ++j){ pf[j]    = __expf(pf[j]    - m_run); rs1 += pf[j]; }
#pragma unroll
    for (int j = 0; j < 8; ++j) { pf[16+j] = __expf(pf[16+j] - m_run); rs2 += pf[16+j]; }
#pragma unroll
    for (int j = 8; j < 16; ++j){ pf[16+j] = __expf(pf[16+j] - m_run); rs3 += pf[16+j]; }
    float rs = (rs0 + rs1) + (rs2 + rs3);
    rs += __shfl_xor(rs, 32, 64);
    l_run += rs;

    unsigned int pb[2][8];
#pragma unroll
    for (int f = 0; f < 2; ++f) {
#pragma unroll
      for (int u = 0; u < 4; ++u) {
        pb[f][2*u]   = cvtpk(pf[f*16 + 4*u + 0], pf[f*16 + 4*u + 1]);
        pb[f][2*u+1] = cvtpk(pf[f*16 + 4*u + 2], pf[f*16 + 4*u + 3]);
      }
      plswap(pb[f][0], pb[f][2]);
      plswap(pb[f][1], pb[f][3]);
      plswap(pb[f][4], pb[f][6]);
      plswap(pb[f][5], pb[f][7]);
    }

#pragma unroll
    for (int s = 0; s < 4; ++s) {
      union { unsigned int u[4]; bf16x8 v; } pbv;
#pragma unroll
      for (int u = 0; u < 4; ++u) pbv.u[u] = pb[s >> 1][(s & 1) * 4 + u];
#pragma unroll
      for (int df = 0; df < 4; ++df) {
        bf16x8 vb = *(const bf16x8*)(VtG + (df*32 + l31) * 72 + s*16 + hi*8);
        __builtin_amdgcn_s_setprio(1);
        acc[df] = __builtin_amdgcn_mfma_f32_32x32x16_bf16(vb, pbv.v, acc[df], 0, 0, 0);
        __builtin_amdgcn_s_setprio(0);
      }
    }
  }

  // ---- split-K combine ----
  __syncthreads();
  float* EXf = (float*)SH;                       // [4][64][68] f32
  float* MLf = (float*)(SH + 35840);             // [4][64][2]  f32
  if (gid == 1) {
    MLf[(wq*64 + l)*2 + 0] = m_run;
    MLf[(wq*64 + l)*2 + 1] = l_run;
#pragma unroll
    for (int df = 0; df < 4; ++df)
#pragma unroll
      for (int u = 0; u < 4; ++u) {
        f32x4 ch = {acc[df][4*u], acc[df][4*u+1], acc[df][4*u+2], acc[df][4*u+3]};
        *(f32x4*)&EXf[(wq*64 + l)*68 + df*16 + u*4] = ch;
      }
  }
  __syncthreads();
  if (gid == 0) {
    float mB = MLf[(wq*64 + l)*2 + 0];
    float lB = MLf[(wq*64 + l)*2 + 1];
    float mF = fmaxf(m_run, mB);
    float a0 = __expf(m_run - mF), a1 = __expf(mB - mF);
    float inv = 1.0f / (l_run * a0 + lB * a1);
    a0 *= inv; a1 *= inv;
#pragma unroll
    for (int df = 0; df < 4; ++df)
#pragma unroll
      for (int u = 0; u < 4; ++u) {
        f32x4 cb = *(const f32x4*)&EXf[(wq*64 + l)*68 + df*16 + u*4];
#pragma unroll
        for (int e = 0; e < 4; ++e)
          acc[df][4*u+e] = acc[df][4*u+e] * a0 + cb[e] * a1;
      }
  }
  __syncthreads();

  // ---- transpose epilogue ----
  unsigned int* OT = (unsigned int*)SH;
  if (gid == 0) {
#pragma unroll
    for (int df = 0; df < 4; ++df)
#pragma unroll
      for (int u = 0; u < 4; ++u) {
        unsigned int d0 = cvtpk(acc[df][4*u+0], acc[df][4*u+1]);
        unsigned int d1 = cvtpk(acc[df][4*u+2], acc[df][4*u+3]);
        uint2 dd; dd.x = d0; dd.y = d1;
        *(uint2*)&OT[(wq*32 + l31)*68 + df*16 + 2*hi + 4*u] = dd;
      }
  }
  __syncthreads();
  {
    const int q = t >> 2, sg = t & 3;
    size_t rowbase = ((size_t)b * TSEQ + q0 + q) * DMODEL + MODE * 512 + h * HDIM;
#pragma unroll
    for (int u = 0; u < 4; ++u) {
      bf16x8 vv = *(const bf16x8*)&OT[q*68 + u*16 + sg*4];
      *(bf16x8*)(AO + rowbase + (u*16 + sg*4)*2) = vv;
    }
  }
}

// grid (8, 16, 2): x=bh (lid%8 -> XCD), y=qt, z: 0=causal+anti, 1=bidir.
__global__ __launch_bounds__(512, 2) void k_attn(
    const unsigned short* __restrict__ Q, const unsigned short* __restrict__ K,
    const unsigned short* __restrict__ VT, unsigned short* __restrict__ AO)
{
  __shared__ __align__(16) unsigned short SH[36864];   // 73,728 B

  const int bh = blockIdx.x;
  const int qt = blockIdx.y;
  if (blockIdx.z == 0) {
    flash_phase<0>(qt, bh, Q, K, VT, AO, SH);
    flash_phase<1>(qt, bh, Q, K, VT, AO, SH);
  } else {
    flash_phase<2>(qt, bh, Q, K, VT, AO, SH);
  }
}

// ---------------------------------------------------------------------------
extern "C" void kernel_launch(void* const* d_in, const int* in_sizes, int n_in,
                              void* d_out, int out_size, void* d_ws, size_t ws_size,
                              hipStream_t stream)
{
  (void)in_sizes; (void)n_in; (void)out_size; (void)ws_size;
  const float* qw  = (const float*)d_in[11];
  const float* kw  = (const float*)d_in[12];

  const size_t S = (size_t)NBR * 2 * NHB * TSEQ * HDIM;       // 6,291,456 elems
  unsigned short* Qs   = (unsigned short*)d_ws;                // S
  unsigned short* Ks   = Qs + S;                               // S
  unsigned short* Vs   = Ks + S;                               // S (holds V^T)
  unsigned short* AO   = Vs + S;                               // S
  unsigned short* Xbf  = AO + S;                               // S (= MROWS*DMODEL)
  unsigned short* Wbf  = Xbf + (size_t)MROWS * DMODEL;         // 9*512*1536
  unsigned short* WObf = Wbf + (size_t)9 * 512 * DMODEL;       // 1536*1536
  float* Cout = (float*)d_out;

  // fused conversion: X | 9 QKV weights | WO
  CVT cv;
  cv.s[0] = (const float*)d_in[0];
  for (int i = 0; i < 9; ++i) cv.s[1 + i] = (const float*)d_in[1 + i];
  cv.s[10] = (const float*)d_in[10];
  k_cvt_all<<<dim3(15360), dim3(256), 0, stream>>>(cv, Xbf, Wbf, WObf);

  // fused QKV projection: [4096, 4608] = X @ Wall^T (V written as V^T, nt)
  k_gemm8<0><<<dim3(32, 24), dim3(512), 0, stream>>>(Xbf, Wbf, Qs, Ks, Vs, nullptr);
  k_rope<<<dim3(6144), dim3(256), 0, stream>>>(Qs, Ks, qw, kw);
  k_attn<<<dim3(8, 16, 2), dim3(512), 0, stream>>>(Qs, Ks, Vs, AO);
  // output projection: [4096, 1536] = AO @ wo^T
  k_gemm8<1><<<dim3(32, 8), dim3(512), 0, stream>>>(AO, WObf, nullptr, nullptr, nullptr, Cout);
}